// Round 8
// baseline (114.953 us; speedup 1.0000x reference)
//
#include <hip/hip_runtime.h>
#include <hip/hip_bf16.h>

// TripletLoss, N=8192, D=256 fp32, targets in [0,128).
// out[0] = mean(relu(dist_ap - dist_an + 0.3)), out[1] = mean(dist_an > dist_ap)
// dist = sqrt(clip(sq_i + sq_j - 2 dot, 1e-12)); sqrt deferred (monotone);
// clipped d2 >= 0 so uint-bit order == float order -> atomicMax/Min unsigned.
//
// R13: back to the PROVEN R10 dispatch structure + PAIR-TILES.
//  - R11/R12 post-mortem: persistent-prep hang = relaxed-load spin can never
//    observe cross-XCD updates (per-XCD L2 not coherent; only RMW/acquire
//    reach the coherent point) -> infinite spin -> container death. Fusion
//    shelved; cross-XCD polls must be RMW-based. No spins anywhere in R13.
//  - Pair-tiles: every triangle row has an EVEN tile count -> fuse (by,2p)
//    and (by,2p+1) into one block. 528 blocks (1.03 rounds of 512 vs 2.06),
//    16 straight phases, SAME 3-buffer rotation + vmcnt(3) ladder (ledger
//    unchanged); B source switches to colBase+128 at group 8.
//  - Mid-block epilogue (tile0) uses raw lgkmcnt(0)+s_barrier only -> DMA
//    groups 8,9 stay in flight UNDER the epilogue = tile1 prologue hidden.
//  - Row-side (pmL/nmL) accumulates across both tiles, flushed once.
//  - R10 carry-overs: 8 waves, wave-tile 64x64, counted-vmcnt single-barrier
//    phases, XCD swizzle (528%8==0), fused finish via arrival counter,
//    SQ_LDS_BANK_CONFLICT ~1.6M = DMA-write artifact (not actionable).

#define N 8192
#define D 256
#define MARGIN 0.3f
#define NPAIR 528   // sum over by=0..31 of (by+1) pairs of 256x128 tiles

typedef __bf16  bf16x8  __attribute__((ext_vector_type(8)));
typedef float   floatx4 __attribute__((ext_vector_type(4)));

__device__ __forceinline__ void load_lds16(const void* g, void* s) {
  __builtin_amdgcn_global_load_lds(
      (const __attribute__((address_space(1))) void*)g,
      (__attribute__((address_space(3))) void*)s, 16, 0, 0);
}

// ---------------- Kernel A: bf16 cast + row sq-norms + init ------------------
__global__ __launch_bounds__(256) void prep_kernel(
    const float* __restrict__ X, unsigned short* __restrict__ Xb,
    float* __restrict__ sq, unsigned* __restrict__ pmax, unsigned* __restrict__ nmin,
    unsigned* __restrict__ cnt) {
  const int t = threadIdx.x;
  if (blockIdx.x == 0 && t == 0) *cnt = 0u;  // re-poison arrival counter
  const int lane = t & 63, wave = t >> 6;
  const int row0 = blockIdx.x * 8 + wave * 2;
#pragma unroll
  for (int r = 0; r < 2; ++r) {
    const int row = row0 + r;
    float4 v = *reinterpret_cast<const float4*>(X + (size_t)row * D + lane * 4);
    ushort4 h;
    {
      __hip_bfloat16 b0 = __float2bfloat16(v.x), b1 = __float2bfloat16(v.y);
      __hip_bfloat16 b2 = __float2bfloat16(v.z), b3 = __float2bfloat16(v.w);
      h.x = *reinterpret_cast<unsigned short*>(&b0);
      h.y = *reinterpret_cast<unsigned short*>(&b1);
      h.z = *reinterpret_cast<unsigned short*>(&b2);
      h.w = *reinterpret_cast<unsigned short*>(&b3);
    }
    *reinterpret_cast<ushort4*>(Xb + (size_t)row * D + lane * 4) = h;
    float s = v.x * v.x + v.y * v.y + v.z * v.z + v.w * v.w;
#pragma unroll
    for (int o = 32; o > 0; o >>= 1) s += __shfl_down(s, o);
    if (lane == 0) {
      sq[row] = s;
      pmax[row] = 0u;
      nmin[row] = 0x7F800000u;  // +inf
    }
  }
}

// ---------------- Kernel B: 256x256 PAIR blocks + fused finish ---------------
__global__ __launch_bounds__(512, 4) void pair_kernel(
    const unsigned short* __restrict__ Xb, const float* __restrict__ sq,
    const int* __restrict__ tgt, unsigned* __restrict__ pmax,
    unsigned* __restrict__ nmin, unsigned* __restrict__ cnt,
    float* __restrict__ out) {
  // T1: XCD-aware swizzle; NPAIR % 8 == 0 (528 = 8*66), bijective.
  const int hw = blockIdx.x;
  const int q = (hw & 7) * (NPAIR / 8) + (hw >> 3);

  // Pair triangle: row by has by+1 pairs; cumulative by*(by+1)/2.
  int by = (int)((sqrtf(8.0f * (float)q + 1.0f) - 1.0f) * 0.5f);
  while ((by + 1) * (by + 2) / 2 <= q) ++by;
  while (by * (by + 1) / 2 > q) --by;
  const int p = q - by * (by + 1) / 2;
  const int rowBase = by * 256;
  const int colBase0 = p * 256, colBase1 = p * 256 + 128;

  const int t = threadIdx.x;
  const int lane = t & 63, wave = t >> 6;
  const int wy = wave >> 1, wx = wave & 1;   // wave-tile 64x64
  const int quad = lane >> 4, l15 = lane & 15;

  // 3-deep rotating buffers: A 256x32 (16KB) x3, B 128x32 (8KB) x3
  __shared__ __align__(16) unsigned short As[3][256 * 32];  // 48 KB
  __shared__ __align__(16) unsigned short Bs[3][128 * 32];  // 24 KB
  __shared__ float sqr[256], sqc[128];
  __shared__ int   tr[256], tc[128];
  __shared__ unsigned pmL[256], nmL[256], pmLc[128], nmLc[128];
  __shared__ unsigned lastFlag;
  __shared__ float fls[8], fps[8];

  if (t < 256) {
    sqr[t] = sq[rowBase + t]; tr[t] = tgt[rowBase + t];
    pmL[t] = 0u; nmL[t] = 0x7F800000u;
  } else if (t < 384) {
    int u = t - 256;
    sqc[u] = sq[colBase0 + u]; tc[u] = tgt[colBase0 + u];
    pmLc[u] = 0u; nmLc[u] = 0x7F800000u;
  }

  const unsigned short* Ag  = Xb + (size_t)rowBase * D;
  const unsigned short* Bg0 = Xb + (size_t)colBase0 * D;
  const unsigned short* Bg1 = Xb + (size_t)colBase1 * D;

  // DMA source pre-swizzle: LDS slot s of row holds global chunk s ^ f(row),
  // f(x) = (x + (x>>2)) & 3; invariant under +16/+64/+128 -> base+immediates.
  const int r0 = t >> 2;                              // 0..127
  const int cA = (t & 3) ^ ((r0 + (r0 >> 2)) & 3);
  const int g0 = r0 * D + cA * 8;                     // elements
  const int wl = wave * 1024;                         // wave-uniform LDS base
  const int fq  = (l15 + (l15 >> 2)) & 3;
  const int aA0 = ((wy * 64 + l15) * 4 + (quad ^ fq)) * 16;  // +mi*1024 +buf*16384
  const int bA0 = ((wx * 64 + l15) * 4 + (quad ^ fq)) * 16;  // +nj*1024 +buf*8192
  const char* AsB = (const char*)As;
  const char* BsB = (const char*)Bs;

  floatx4 acc[4][4];
#pragma unroll
  for (int mi = 0; mi < 4; ++mi)
#pragma unroll
    for (int nj = 0; nj < 4; ++nj)
      acc[mi][nj] = (floatx4){0.f, 0.f, 0.f, 0.f};

  // Shared epilogue-accumulate (reads acc + sqr/tr + CURRENT sqc/tc;
  // pushes into pmL/nmL (rows, shared across both tiles) and pmLc/nmLc).
  auto epi_accum = [&]() {
    float sqc_l[4]; int tc_l[4];
#pragma unroll
    for (int nj = 0; nj < 4; ++nj) {
      int jl = wx * 64 + nj * 16 + l15;
      sqc_l[nj] = sqc[jl];
      tc_l[nj]  = tc[jl];
    }
    float pm[16], nm[16], cmP[4], cmN[4];
#pragma unroll
    for (int s = 0; s < 16; ++s) { pm[s] = 0.f; nm[s] = __builtin_huge_valf(); }
#pragma unroll
    for (int nj = 0; nj < 4; ++nj) { cmP[nj] = 0.f; cmN[nj] = __builtin_huge_valf(); }
#pragma unroll
    for (int mi = 0; mi < 4; ++mi) {
#pragma unroll
      for (int r = 0; r < 4; ++r) {
        int il = wy * 64 + mi * 16 + quad * 4 + r;
        float si = sqr[il];
        int   ti = tr[il];
        int   s  = mi * 4 + r;
#pragma unroll
        for (int nj = 0; nj < 4; ++nj) {
          float d2 = fmaf(-2.f, acc[mi][nj][r], si + sqc_l[nj]);  // unclipped
          bool same = (ti == tc_l[nj]);
          // 0-identity pre-clip safe for max: diagonal guarantees true
          // pmax >= 1e-12; clip re-applied before the ordered atomics.
          float selP = same ? d2 : 0.f;
          float selN = same ? __builtin_huge_valf() : d2;
          pm[s]   = fmaxf(pm[s], selP);
          nm[s]   = fminf(nm[s], selN);
          cmP[nj] = fmaxf(cmP[nj], selP);
          cmN[nj] = fminf(cmN[nj], selN);
        }
      }
    }
    // row-side halving butterfly across 16 lanes of each quad group
#pragma unroll
    for (int m = 8; m >= 1; m >>= 1) {
#pragma unroll
      for (int j = 0; j < m; ++j) {
        bool up = (l15 & m) != 0;
        float sp = up ? pm[j] : pm[j + m];
        float sn = up ? nm[j] : nm[j + m];
        float rp = __shfl_xor(sp, m);
        float rn = __shfl_xor(sn, m);
        float kp = up ? pm[j + m] : pm[j];
        float kn = up ? nm[j + m] : nm[j];
        pm[j] = fmaxf(kp, rp);
        nm[j] = fminf(kn, rn);
      }
    }
    {
      // clip BEFORE uint-ordered atomics (sign trick needs >= 0)
      int rowIdx = wy * 64 + ((l15 >> 2) << 4) + (quad << 2) + (l15 & 3);
      atomicMax(&pmL[rowIdx], __float_as_uint(fmaxf(pm[0], 1e-12f)));
      atomicMin(&nmL[rowIdx], __float_as_uint(fmaxf(nm[0], 1e-12f)));
    }
    // col-side: reduce across quads
#pragma unroll
    for (int nj = 0; nj < 4; ++nj) {
      cmP[nj] = fmaxf(cmP[nj], __shfl_xor(cmP[nj], 16));
      cmP[nj] = fmaxf(cmP[nj], __shfl_xor(cmP[nj], 32));
      cmN[nj] = fminf(cmN[nj], __shfl_xor(cmN[nj], 16));
      cmN[nj] = fminf(cmN[nj], __shfl_xor(cmN[nj], 32));
    }
    {
      float vP = (quad == 0) ? cmP[0] : (quad == 1) ? cmP[1] : (quad == 2) ? cmP[2] : cmP[3];
      float vN = (quad == 0) ? cmN[0] : (quad == 1) ? cmN[1] : (quad == 2) ? cmN[2] : cmN[3];
      int colIdx = wx * 64 + quad * 16 + l15;
      atomicMax(&pmLc[colIdx], __float_as_uint(fmaxf(vP, 1e-12f)));
      atomicMin(&nmLc[colIdx], __float_as_uint(fmaxf(vN, 1e-12f)));
    }
  };

  // 3 DMA loads/thread/group: A rows r0, r0+128; B row r0. Groups 0..15;
  // ko wraps at 8 (tile0 k / tile1 k); B source per call site.
#define ISSUE_DMA(ph, Bp) do {                                               \
    const int ko_ = ((ph) & 7) * 32;                                         \
    char* an_ = (char*)As[(ph) % 3];                                         \
    char* bn_ = (char*)Bs[(ph) % 3];                                         \
    load_lds16(Ag + g0 + ko_,           an_ + wl);                           \
    load_lds16(Ag + g0 + 128 * D + ko_, an_ + wl + 8192);                    \
    load_lds16((Bp) + g0 + ko_,         bn_ + wl);                           \
  } while (0)

  // Single barrier per phase (R8/R10 ledger, 16 straight phases):
  //  * vmcnt(VM) BEFORE barrier drains this wave's group k (3 loads; group
  //    k+1 outstanding -> VM=3; tail VM=0). Epilogue atomics are NEWER than
  //    any DMA group, so vmcnt(3) still drains the needed group at PHASE(8).
  //  * issue k+2 after the barrier overwrites buf (k-1)%3; every wave
  //    secured its phase-(k-1) ds_reads (lgkmcnt(0)) before arriving.
#define PHASE(kk, VM, ...) do {                                              \
    asm volatile("s_waitcnt vmcnt(" #VM ")" ::: "memory");                   \
    __builtin_amdgcn_s_barrier();                                            \
    __builtin_amdgcn_sched_barrier(0);                                       \
    const char* ab_ = AsB + ((kk) % 3) * 16384;                              \
    const char* bb_ = BsB + ((kk) % 3) * 8192;                               \
    bf16x8 a_[4], b_[4];                                                     \
    _Pragma("unroll")                                                        \
    for (int mi = 0; mi < 4; ++mi)                                           \
      a_[mi] = *reinterpret_cast<const bf16x8*>(ab_ + aA0 + mi * 1024);      \
    _Pragma("unroll")                                                        \
    for (int nj = 0; nj < 4; ++nj)                                           \
      b_[nj] = *reinterpret_cast<const bf16x8*>(bb_ + bA0 + nj * 1024);      \
    __VA_ARGS__;                                                             \
    asm volatile("s_waitcnt lgkmcnt(0)" ::: "memory");                       \
    __builtin_amdgcn_sched_barrier(0);                                       \
    __builtin_amdgcn_s_setprio(1);                                           \
    _Pragma("unroll")                                                        \
    for (int mi = 0; mi < 4; ++mi)                                           \
      _Pragma("unroll")                                                      \
      for (int nj = 0; nj < 4; ++nj)                                         \
        acc[mi][nj] = __builtin_amdgcn_mfma_f32_16x16x32_bf16(               \
            a_[mi], b_[nj], acc[mi][nj], 0, 0, 0);                           \
    __builtin_amdgcn_s_setprio(0);                                           \
    __builtin_amdgcn_sched_barrier(0);                                       \
  } while (0)

  // prologue: groups 0,1 in flight
  ISSUE_DMA(0, Bg0);
  ISSUE_DMA(1, Bg0);

  // ---- tile0: phases 0..7 ----
  PHASE(0, 3, ISSUE_DMA(2, Bg0));
  PHASE(1, 3, ISSUE_DMA(3, Bg0));
  PHASE(2, 3, ISSUE_DMA(4, Bg0));
  PHASE(3, 3, ISSUE_DMA(5, Bg0));
  PHASE(4, 3, ISSUE_DMA(6, Bg0));
  PHASE(5, 3, ISSUE_DMA(7, Bg0));
  PHASE(6, 3, ISSUE_DMA(8, Bg1));   // groups 8,9 = tile1 k=0,1
  PHASE(7, 3, ISSUE_DMA(9, Bg1));

  // ---- mid epilogue (tile0) -- raw barriers only: DMA 8,9 stay in flight
  epi_accum();
  asm volatile("s_waitcnt lgkmcnt(0)" ::: "memory");
  __builtin_amdgcn_s_barrier();          // all LDS atomics visible
  if (t < 128) {
    // flush tile0 cols (fire-and-forget RMW, coherent at LLC), then re-init
    atomicMax(&pmax[colBase0 + t], pmLc[t]);
    atomicMin(&nmin[colBase0 + t], nmLc[t]);
    pmLc[t] = 0u; nmLc[t] = 0x7F800000u;
  } else if (t >= 256 && t < 384) {
    int u = t - 256;
    sqc[u] = sq[colBase1 + u]; tc[u] = tgt[colBase1 + u];
  }
#pragma unroll
  for (int mi = 0; mi < 4; ++mi)
#pragma unroll
    for (int nj = 0; nj < 4; ++nj)
      acc[mi][nj] = (floatx4){0.f, 0.f, 0.f, 0.f};
  asm volatile("s_waitcnt lgkmcnt(0)" ::: "memory");  // re-init/reload drain
  // PHASE(8)'s vmcnt(3)+barrier completes the handoff (drains DMA 8).

  // ---- tile1: phases 8..15 ----
  PHASE(8,  3, ISSUE_DMA(10, Bg1));
  PHASE(9,  3, ISSUE_DMA(11, Bg1));
  PHASE(10, 3, ISSUE_DMA(12, Bg1));
  PHASE(11, 3, ISSUE_DMA(13, Bg1));
  PHASE(12, 3, ISSUE_DMA(14, Bg1));
  PHASE(13, 3, ISSUE_DMA(15, Bg1));
  PHASE(14, 3, (void)0);
  PHASE(15, 0, (void)0);

#undef PHASE
#undef ISSUE_DMA

  // ---- final epilogue (tile1) + row flush + arrival + finish ----
  epi_accum();
  asm volatile("s_waitcnt lgkmcnt(0)" ::: "memory");
  __builtin_amdgcn_s_barrier();

  // Global atomics with captured returns (sc0; commit at coherent point).
  unsigned keep = 0u;
  if (t < 256) {
    unsigned o1 = atomicMax(&pmax[rowBase + t], pmL[t]);   // rows: both tiles
    unsigned o2 = atomicMin(&nmin[rowBase + t], nmL[t]);
    keep = o1 ^ o2;
  } else if (t < 384) {
    int u = t - 256;
    unsigned o3 = atomicMax(&pmax[colBase1 + u], pmLc[u]); // tile1 cols
    unsigned o4 = atomicMin(&nmin[colBase1 + u], nmLc[u]);
    keep = o3 ^ o4;
  }
  asm volatile("" :: "v"(keep));  // keep returns live (no DCE of sc0)
  asm volatile("s_waitcnt vmcnt(0)" ::: "memory");
  __syncthreads();

  // arrival counter: all RMWs committed at the coherent point; no dirty
  // plain stores exist -> no wbl2 fence needed (the R3/R4 trap).
  if (t == 0) lastFlag = (atomicAdd(cnt, 1u) == NPAIR - 1u) ? 1u : 0u;
  __syncthreads();

  if (lastFlag) {
    // ---- fused finish: agent-scope coherent loads, fully pipelined ----
    float lsum = 0.f, psum = 0.f;
#pragma unroll 4
    for (int i = t; i < N; i += 512) {
      unsigned pu = __hip_atomic_load(&pmax[i], __ATOMIC_RELAXED, __HIP_MEMORY_SCOPE_AGENT);
      unsigned nu = __hip_atomic_load(&nmin[i], __ATOMIC_RELAXED, __HIP_MEMORY_SCOPE_AGENT);
      float ap = sqrtf(__uint_as_float(pu));
      float an = sqrtf(__uint_as_float(nu));
      lsum += fmaxf(ap - an + MARGIN, 0.f);
      psum += (an > ap) ? 1.f : 0.f;
    }
#pragma unroll
    for (int o = 32; o > 0; o >>= 1) {
      lsum += __shfl_down(lsum, o);
      psum += __shfl_down(psum, o);
    }
    if ((t & 63) == 0) { fls[t >> 6] = lsum; fps[t >> 6] = psum; }
    __syncthreads();
    if (t == 0) {
      float L = 0.f, P = 0.f;
#pragma unroll
      for (int wv = 0; wv < 8; ++wv) { L += fls[wv]; P += fps[wv]; }
      out[0] = L * (1.0f / (float)N);
      out[1] = P * (1.0f / (float)N);
    }
  }
}

extern "C" void kernel_launch(void* const* d_in, const int* in_sizes, int n_in,
                              void* d_out, int out_size, void* d_ws, size_t ws_size,
                              hipStream_t stream) {
  const float* X  = (const float*)d_in[0];
  const int* tgt  = (const int*)d_in[1];
  float* out      = (float*)d_out;

  char* ws = (char*)d_ws;
  unsigned short* Xb = (unsigned short*)ws;                    // 4 MiB
  float*    sq    = (float*)(ws + 4194304);                    // 32 KiB
  unsigned* pmax  = (unsigned*)(ws + 4194304 + 32768);         // 32 KiB
  unsigned* nmin  = (unsigned*)(ws + 4194304 + 65536);         // 32 KiB
  unsigned* cnt   = (unsigned*)(ws + 4194304 + 98304);         // 4 B

  prep_kernel<<<1024, 256, 0, stream>>>(X, Xb, sq, pmax, nmin, cnt);
  pair_kernel<<<NPAIR, 512, 0, stream>>>(Xb, sq, tgt, pmax, nmin, cnt, out);
}

// Round 9
// 102.691 us; speedup vs baseline: 1.1194x; 1.1194x over previous
//
#include <hip/hip_runtime.h>
#include <hip/hip_bf16.h>

// TripletLoss, N=8192, D=256 fp32, targets in [0,128).
// out[0] = mean(relu(dist_ap - dist_an + 0.3)), out[1] = mean(dist_an > dist_ap)
// dist = sqrt(clip(sq_i + sq_j - 2 dot, 1e-12)); sqrt deferred (monotone);
// clipped d2 >= 0 so uint-bit order == float order -> atomicMax/Min unsigned.
//
// R14 = R10 structure + LDS DIET so 2 blocks/CU truly co-reside.
//  - R13 post-mortem: (a) 528 blocks on 512 slots = tail cliff (16
//    stragglers double the dispatch) -> pair-tiles reverted; (b) occupancy
//    21% proves 80384B LDS blocks were 1/CU since R9 -> every sync stall
//    fully exposed. Fix: delete the LDS reduction arrays (each lane pushes
//    its butterfly result DIRECTLY to the global atomics; the LDS stage
//    addressed a bottleneck we don't have) + u8 targets: 80384 -> ~75.7KB,
//    x2 = 151KB < 160KiB with slack for runtime reservation.
//  - Everything else byte-identical to R10 (score 99.4, absmax 0): 1056
//    256x128 tiles, 8 waves, wave-tile 64x64, 3-deep buffers, counted-vmcnt
//    depth-2 (ladder 3 x7, 0), single barrier/phase, XCD swizzle, fused
//    finish via arrival counter.
//  - Score model: ~44.8us poison fill (uncontrollable, in-window) + prep
//    + gaps + tile. Attackable = prep + tile.
//  - SQ_LDS_BANK_CONFLICT ~1.6M = global_load_lds DMA-write artifact.

#define N 8192
#define D 256
#define MARGIN 0.3f
#define NBLK 1056  // sum over by=0..31 of (2*by+2) 256x128 tiles

typedef __bf16  bf16x8  __attribute__((ext_vector_type(8)));
typedef float   floatx4 __attribute__((ext_vector_type(4)));

__device__ __forceinline__ void load_lds16(const void* g, void* s) {
  __builtin_amdgcn_global_load_lds(
      (const __attribute__((address_space(1))) void*)g,
      (__attribute__((address_space(3))) void*)s, 16, 0, 0);
}

// ---------------- Kernel A: bf16 cast + row sq-norms + init ------------------
__global__ __launch_bounds__(256) void prep_kernel(
    const float* __restrict__ X, unsigned short* __restrict__ Xb,
    float* __restrict__ sq, unsigned* __restrict__ pmax, unsigned* __restrict__ nmin,
    unsigned* __restrict__ cnt) {
  const int t = threadIdx.x;
  if (blockIdx.x == 0 && t == 0) *cnt = 0u;  // re-poison arrival counter
  const int lane = t & 63, wave = t >> 6;
  const int row0 = blockIdx.x * 8 + wave * 2;
#pragma unroll
  for (int r = 0; r < 2; ++r) {
    const int row = row0 + r;
    float4 v = *reinterpret_cast<const float4*>(X + (size_t)row * D + lane * 4);
    ushort4 h;
    {
      __hip_bfloat16 b0 = __float2bfloat16(v.x), b1 = __float2bfloat16(v.y);
      __hip_bfloat16 b2 = __float2bfloat16(v.z), b3 = __float2bfloat16(v.w);
      h.x = *reinterpret_cast<unsigned short*>(&b0);
      h.y = *reinterpret_cast<unsigned short*>(&b1);
      h.z = *reinterpret_cast<unsigned short*>(&b2);
      h.w = *reinterpret_cast<unsigned short*>(&b3);
    }
    *reinterpret_cast<ushort4*>(Xb + (size_t)row * D + lane * 4) = h;
    float s = v.x * v.x + v.y * v.y + v.z * v.z + v.w * v.w;
#pragma unroll
    for (int o = 32; o > 0; o >>= 1) s += __shfl_down(s, o);
    if (lane == 0) {
      sq[row] = s;
      pmax[row] = 0u;
      nmin[row] = 0x7F800000u;  // +inf
    }
  }
}

// ---------------- Kernel B: 256x128 tiles, 8 waves + fused finish ------------
__global__ __launch_bounds__(512, 4) void tile_kernel(
    const unsigned short* __restrict__ Xb, const float* __restrict__ sq,
    const int* __restrict__ tgt, unsigned* __restrict__ pmax,
    unsigned* __restrict__ nmin, unsigned* __restrict__ cnt,
    float* __restrict__ out) {
  // T1: XCD-aware swizzle; NBLK % 8 == 0 (1056 = 8*132), bijective.
  const int hw = blockIdx.x;
  const int bi = (hw & 7) * (NBLK / 8) + (hw >> 3);

  // Triangle cover by 256-row x 128-col tiles: tile (by,bx) exists for
  // bx in [0, 2*by+2). Cumulative count C(by) = by*(by+1).
  int by = (int)((sqrtf(4.0f * (float)bi + 1.0f) - 1.0f) * 0.5f);
  while ((by + 1) * (by + 2) <= bi) ++by;
  while (by * (by + 1) > bi) --by;
  const int bx = bi - by * (by + 1);
  const int rowBase = by * 256, colBase = bx * 128;

  const int t = threadIdx.x;
  const int lane = t & 63, wave = t >> 6;
  const int wy = wave >> 1, wx = wave & 1;   // wave-tile 64x64
  const int quad = lane >> 4, l15 = lane & 15;

  // 3-deep rotating buffers: A 256x32 (16KB) x3, B 128x32 (8KB) x3
  __shared__ __align__(16) unsigned short As[3][256 * 32];  // 48 KB
  __shared__ __align__(16) unsigned short Bs[3][128 * 32];  // 24 KB
  __shared__ float sqr[256], sqc[128];
  __shared__ unsigned char tr8[256], tc8[128];   // targets in [0,128) fit u8
  __shared__ unsigned lastFlag;
  __shared__ float fls[8], fps[8];
  // NO LDS reduction arrays: butterfly results go straight to global RMWs.

  if (t < 256) {
    sqr[t] = sq[rowBase + t]; tr8[t] = (unsigned char)tgt[rowBase + t];
  } else if (t < 384) {
    int u = t - 256;
    sqc[u] = sq[colBase + u]; tc8[u] = (unsigned char)tgt[colBase + u];
  }

  const unsigned short* Ag = Xb + (size_t)rowBase * D;
  const unsigned short* Bg = Xb + (size_t)colBase * D;

  // DMA source pre-swizzle: LDS slot s of row holds global chunk s ^ f(row),
  // f(x) = (x + (x>>2)) & 3; invariant under +16/+64/+128 -> base+immediates.
  const int r0 = t >> 2;                              // 0..127
  const int cA = (t & 3) ^ ((r0 + (r0 >> 2)) & 3);
  const int g0 = r0 * D + cA * 8;                     // elements
  const int wl = wave * 1024;                         // wave-uniform LDS base
  const int fq  = (l15 + (l15 >> 2)) & 3;
  const int aA0 = ((wy * 64 + l15) * 4 + (quad ^ fq)) * 16;  // +mi*1024 +buf*16384
  const int bA0 = ((wx * 64 + l15) * 4 + (quad ^ fq)) * 16;  // +nj*1024 +buf*8192
  const char* AsB = (const char*)As;
  const char* BsB = (const char*)Bs;

  floatx4 acc[4][4];
#pragma unroll
  for (int mi = 0; mi < 4; ++mi)
#pragma unroll
    for (int nj = 0; nj < 4; ++nj)
      acc[mi][nj] = (floatx4){0.f, 0.f, 0.f, 0.f};

  // 3 DMA loads/thread/phase: A rows r0, r0+128; B row r0 (512 thr = 128 rows)
#define ISSUE_DMA(ph) do {                                                   \
    const int ko_ = (ph) * 32;                                               \
    char* an_ = (char*)As[(ph) % 3];                                         \
    char* bn_ = (char*)Bs[(ph) % 3];                                         \
    load_lds16(Ag + g0 + ko_,           an_ + wl);                           \
    load_lds16(Ag + g0 + 128 * D + ko_, an_ + wl + 8192);                    \
    load_lds16(Bg + g0 + ko_,           bn_ + wl);                           \
  } while (0)

  // Single barrier per phase (R8/R10 ledger): vmcnt(own group) BEFORE the
  // barrier -> tile k%3 valid cross-wave at exit; ISSUE k+2 after barrier
  // overwrites buf (k-1)%3 whose reads all waves secured via lgkmcnt(0).
#define PHASE(kk, VM) do {                                                   \
    asm volatile("s_waitcnt vmcnt(" #VM ")" ::: "memory");                   \
    __builtin_amdgcn_s_barrier();                                            \
    __builtin_amdgcn_sched_barrier(0);                                       \
    const char* ab_ = AsB + ((kk) % 3) * 16384;                              \
    const char* bb_ = BsB + ((kk) % 3) * 8192;                               \
    bf16x8 a_[4], b_[4];                                                     \
    _Pragma("unroll")                                                        \
    for (int mi = 0; mi < 4; ++mi)                                           \
      a_[mi] = *reinterpret_cast<const bf16x8*>(ab_ + aA0 + mi * 1024);      \
    _Pragma("unroll")                                                        \
    for (int nj = 0; nj < 4; ++nj)                                           \
      b_[nj] = *reinterpret_cast<const bf16x8*>(bb_ + bA0 + nj * 1024);      \
    if ((kk) < 6) ISSUE_DMA((kk) + 2);                                       \
    asm volatile("s_waitcnt lgkmcnt(0)" ::: "memory");                       \
    __builtin_amdgcn_sched_barrier(0);                                       \
    __builtin_amdgcn_s_setprio(1);                                           \
    _Pragma("unroll")                                                        \
    for (int mi = 0; mi < 4; ++mi)                                           \
      _Pragma("unroll")                                                      \
      for (int nj = 0; nj < 4; ++nj)                                         \
        acc[mi][nj] = __builtin_amdgcn_mfma_f32_16x16x32_bf16(               \
            a_[mi], b_[nj], acc[mi][nj], 0, 0, 0);                           \
    __builtin_amdgcn_s_setprio(0);                                           \
    __builtin_amdgcn_sched_barrier(0);                                       \
  } while (0)

  // prologue: phases 0 and 1 in flight (6 loads/thread outstanding)
  ISSUE_DMA(0);
  ISSUE_DMA(1);

  PHASE(0, 3);
  PHASE(1, 3);
  PHASE(2, 3);
  PHASE(3, 3);
  PHASE(4, 3);
  PHASE(5, 3);
  PHASE(6, 3);
  PHASE(7, 0);

#undef PHASE
#undef ISSUE_DMA

  // ---- two-sided epilogue on UNclipped d2 (clip re-applied at pushes) ----
  // sqr/sqc/tr8/tc8 were written at block start and synced by the PHASE
  // barriers; epilogue is register-only until the direct global RMWs.
  float sqc_l[4]; int tc_l[4];
#pragma unroll
  for (int nj = 0; nj < 4; ++nj) {
    int jl = wx * 64 + nj * 16 + l15;
    sqc_l[nj] = sqc[jl];
    tc_l[nj]  = tc8[jl];
  }

  float pm[16], nm[16], cmP[4], cmN[4];
#pragma unroll
  for (int s = 0; s < 16; ++s) { pm[s] = 0.f; nm[s] = __builtin_huge_valf(); }
#pragma unroll
  for (int nj = 0; nj < 4; ++nj) { cmP[nj] = 0.f; cmN[nj] = __builtin_huge_valf(); }

#pragma unroll
  for (int mi = 0; mi < 4; ++mi) {
#pragma unroll
    for (int r = 0; r < 4; ++r) {
      int il = wy * 64 + mi * 16 + quad * 4 + r;
      float si = sqr[il];
      int   ti = tr8[il];
      int   s  = mi * 4 + r;
#pragma unroll
      for (int nj = 0; nj < 4; ++nj) {
        float d2 = fmaf(-2.f, acc[mi][nj][r], si + sqc_l[nj]);  // unclipped
        bool same = (ti == tc_l[nj]);
        // 0-identity pre-clip safe for max: diagonal guarantees true
        // pmax >= 1e-12; clip re-applied before the ordered atomics.
        float selP = same ? d2 : 0.f;
        float selN = same ? __builtin_huge_valf() : d2;
        pm[s]   = fmaxf(pm[s], selP);
        nm[s]   = fminf(nm[s], selN);
        cmP[nj] = fmaxf(cmP[nj], selP);
        cmN[nj] = fminf(cmN[nj], selN);
      }
    }
  }

  // row-side halving butterfly across 16 lanes of each quad group
#pragma unroll
  for (int m = 8; m >= 1; m >>= 1) {
#pragma unroll
    for (int j = 0; j < m; ++j) {
      bool up = (l15 & m) != 0;
      float sp = up ? pm[j] : pm[j + m];
      float sn = up ? nm[j] : nm[j + m];
      float rp = __shfl_xor(sp, m);
      float rn = __shfl_xor(sn, m);
      float kp = up ? pm[j + m] : pm[j];
      float kn = up ? nm[j + m] : nm[j];
      pm[j] = fmaxf(kp, rp);
      nm[j] = fminf(kn, rn);
    }
  }

  // DIRECT global RMWs (clip first: sign trick needs >= 0). Returns captured
  // (sc0) so vmcnt(0) below proves commit at the device-coherent point.
  unsigned keep;
  {
    int rowIdx = wy * 64 + ((l15 >> 2) << 4) + (quad << 2) + (l15 & 3);
    unsigned o1 = atomicMax(&pmax[rowBase + rowIdx], __float_as_uint(fmaxf(pm[0], 1e-12f)));
    unsigned o2 = atomicMin(&nmin[rowBase + rowIdx], __float_as_uint(fmaxf(nm[0], 1e-12f)));
    keep = o1 ^ o2;
  }

  // col-side: reduce across quads, then direct global RMW
#pragma unroll
  for (int nj = 0; nj < 4; ++nj) {
    cmP[nj] = fmaxf(cmP[nj], __shfl_xor(cmP[nj], 16));
    cmP[nj] = fmaxf(cmP[nj], __shfl_xor(cmP[nj], 32));
    cmN[nj] = fminf(cmN[nj], __shfl_xor(cmN[nj], 16));
    cmN[nj] = fminf(cmN[nj], __shfl_xor(cmN[nj], 32));
  }
  {
    float vP = (quad == 0) ? cmP[0] : (quad == 1) ? cmP[1] : (quad == 2) ? cmP[2] : cmP[3];
    float vN = (quad == 0) ? cmN[0] : (quad == 1) ? cmN[1] : (quad == 2) ? cmN[2] : cmN[3];
    int colIdx = wx * 64 + quad * 16 + l15;
    unsigned o3 = atomicMax(&pmax[colBase + colIdx], __float_as_uint(fmaxf(vP, 1e-12f)));
    unsigned o4 = atomicMin(&nmin[colBase + colIdx], __float_as_uint(fmaxf(vN, 1e-12f)));
    keep ^= o3 ^ o4;
  }
  asm volatile("" :: "v"(keep));  // keep returns live (no DCE of sc0)
  asm volatile("s_waitcnt vmcnt(0)" ::: "memory");
  __syncthreads();

  // arrival counter: all RMWs committed at the coherent point; no dirty
  // plain stores exist -> no wbl2 fence needed (the R3/R4 trap).
  if (t == 0) lastFlag = (atomicAdd(cnt, 1u) == NBLK - 1u) ? 1u : 0u;
  __syncthreads();

  if (lastFlag) {
    // ---- fused finish: agent-scope coherent loads, fully pipelined ----
    float lsum = 0.f, psum = 0.f;
#pragma unroll 4
    for (int i = t; i < N; i += 512) {
      unsigned pu = __hip_atomic_load(&pmax[i], __ATOMIC_RELAXED, __HIP_MEMORY_SCOPE_AGENT);
      unsigned nu = __hip_atomic_load(&nmin[i], __ATOMIC_RELAXED, __HIP_MEMORY_SCOPE_AGENT);
      float ap = sqrtf(__uint_as_float(pu));
      float an = sqrtf(__uint_as_float(nu));
      lsum += fmaxf(ap - an + MARGIN, 0.f);
      psum += (an > ap) ? 1.f : 0.f;
    }
#pragma unroll
    for (int o = 32; o > 0; o >>= 1) {
      lsum += __shfl_down(lsum, o);
      psum += __shfl_down(psum, o);
    }
    if ((t & 63) == 0) { fls[t >> 6] = lsum; fps[t >> 6] = psum; }
    __syncthreads();
    if (t == 0) {
      float L = 0.f, P = 0.f;
#pragma unroll
      for (int wv = 0; wv < 8; ++wv) { L += fls[wv]; P += fps[wv]; }
      out[0] = L * (1.0f / (float)N);
      out[1] = P * (1.0f / (float)N);
    }
  }
}

extern "C" void kernel_launch(void* const* d_in, const int* in_sizes, int n_in,
                              void* d_out, int out_size, void* d_ws, size_t ws_size,
                              hipStream_t stream) {
  const float* X  = (const float*)d_in[0];
  const int* tgt  = (const int*)d_in[1];
  float* out      = (float*)d_out;

  char* ws = (char*)d_ws;
  unsigned short* Xb = (unsigned short*)ws;                    // 4 MiB
  float*    sq    = (float*)(ws + 4194304);                    // 32 KiB
  unsigned* pmax  = (unsigned*)(ws + 4194304 + 32768);         // 32 KiB
  unsigned* nmin  = (unsigned*)(ws + 4194304 + 65536);         // 32 KiB
  unsigned* cnt   = (unsigned*)(ws + 4194304 + 98304);         // 4 B

  prep_kernel<<<1024, 256, 0, stream>>>(X, Xb, sq, pmax, nmin, cnt);
  tile_kernel<<<NBLK, 512, 0, stream>>>(Xb, sq, tgt, pmax, nmin, cnt, out);
}